// Round 3
// baseline (1379.330 us; speedup 1.0000x reference)
//
#include <hip/hip_runtime.h>
#include <cstdint>
#include <cstddef>

#define S_LEN 4096
#define BATCH 4
#define DMODEL 512
#define THRESHV 0.95f
#define NSPLIT 8
#define NCHUNK (S_LEN / NSPLIT)

// =====================================================================
// Kernel 1: fused QKV projection.  128x128 block tile, 8x8 per thread.
// q/k/v[b][s][n] = sum_d x[s][b][d] * w[n][d] + bias[n]
// x is [S,B,D]; row m = s*B+b is contiguous in d.  Output re-laid out
// as [B][S][D] so kernels 2/3 read per-batch rows contiguously.
// =====================================================================
__global__ __launch_bounds__(256)
void qkv_gemm_kernel(const float* __restrict__ x,
                     const float* __restrict__ qw, const float* __restrict__ qbias,
                     const float* __restrict__ kw, const float* __restrict__ kbias,
                     const float* __restrict__ vw, const float* __restrict__ vbias,
                     float* __restrict__ qo, float* __restrict__ ko, float* __restrict__ vo)
{
    constexpr int BM = 128, BN = 128, BK = 32;
    const float* w; const float* bias; float* out;
    if (blockIdx.z == 0)      { w = qw; bias = qbias; out = qo; }
    else if (blockIdx.z == 1) { w = kw; bias = kbias; out = ko; }
    else                      { w = vw; bias = vbias; out = vo; }

    __shared__ float As[BK][BM + 4];   // stride 132 floats; rows 16B-aligned
    __shared__ float Bs[BK][BN + 4];

    const int tid = threadIdx.x;
    const int tx = tid & 15, ty = tid >> 4;   // 16x16 thread grid
    const int lr = tid >> 3;                  // 0..31
    const int lc = (tid & 7) << 2;            // 0,4,...,28 (col in BK)
    const int m0 = blockIdx.x * BM;
    const int n0 = blockIdx.y * BN;

    float acc[8][8] = {};

    for (int k0 = 0; k0 < DMODEL; k0 += BK) {
        #pragma unroll
        for (int p = 0; p < 4; ++p) {
            const int row = lr + p * 32;
            const float4 av = *(const float4*)(x + (size_t)(m0 + row) * DMODEL + k0 + lc);
            const float4 bv = *(const float4*)(w + (size_t)(n0 + row) * DMODEL + k0 + lc);
            As[lc+0][row] = av.x; As[lc+1][row] = av.y; As[lc+2][row] = av.z; As[lc+3][row] = av.w;
            Bs[lc+0][row] = bv.x; Bs[lc+1][row] = bv.y; Bs[lc+2][row] = bv.z; Bs[lc+3][row] = bv.w;
        }
        __syncthreads();
        #pragma unroll
        for (int kk = 0; kk < BK; ++kk) {
            const float4 a0 = *(const float4*)&As[kk][ty << 2];
            const float4 a1 = *(const float4*)&As[kk][(ty << 2) + 64];
            const float4 b0 = *(const float4*)&Bs[kk][tx << 2];
            const float4 b1 = *(const float4*)&Bs[kk][(tx << 2) + 64];
            const float a[8]  = {a0.x, a0.y, a0.z, a0.w, a1.x, a1.y, a1.z, a1.w};
            const float bb[8] = {b0.x, b0.y, b0.z, b0.w, b1.x, b1.y, b1.z, b1.w};
            #pragma unroll
            for (int i = 0; i < 8; ++i)
                #pragma unroll
                for (int j = 0; j < 8; ++j)
                    acc[i][j] = fmaf(a[i], bb[j], acc[i][j]);
        }
        __syncthreads();
    }

    const float4 bias0 = *(const float4*)(bias + n0 + (tx << 2));
    const float4 bias1 = *(const float4*)(bias + n0 + (tx << 2) + 64);
    #pragma unroll
    for (int i = 0; i < 8; ++i) {
        const int m = m0 + ((i < 4) ? (ty << 2) + i : 64 + (ty << 2) + (i - 4));
        const int s = m >> 2, b = m & 3;
        float* orow = out + ((size_t)b * S_LEN + s) * DMODEL;
        float4 r0, r1;
        r0.x = acc[i][0] + bias0.x; r0.y = acc[i][1] + bias0.y;
        r0.z = acc[i][2] + bias0.z; r0.w = acc[i][3] + bias0.w;
        r1.x = acc[i][4] + bias1.x; r1.y = acc[i][5] + bias1.y;
        r1.z = acc[i][6] + bias1.z; r1.w = acc[i][7] + bias1.w;
        *(float4*)(orow + n0 + (tx << 2))      = r0;
        *(float4*)(orow + n0 + (tx << 2) + 64) = r1;
    }
}

// =====================================================================
// Kernel 2: scores = Q K^T per batch, fused running max/argmax.
// 128x128 block tile, 8x8 per thread.  Each block: one batch, 128 query
// rows, one chunk of NCHUNK keys.  First-occurrence argmax: per-thread
// scan ascending in t with strict >; cross-lane shfl reduce with
// smaller-index tie-break (each row's 16 partials live in one wave).
// =====================================================================
__global__ __launch_bounds__(256)
void score_argmax_kernel(const float* __restrict__ q, const float* __restrict__ k,
                         float* __restrict__ pmax, int* __restrict__ pidx)
{
    constexpr int BM = 128, BN = 128, BK = 32;
    const int b  = blockIdx.y;
    const int s0 = blockIdx.x * BM;
    const int t0 = blockIdx.z * NCHUNK;
    const float* Q = q + (size_t)b * S_LEN * DMODEL;
    const float* K = k + (size_t)b * S_LEN * DMODEL;

    __shared__ float Qs[BK][BM + 4];
    __shared__ float Ks[BK][BN + 4];

    const int tid = threadIdx.x;
    const int tx = tid & 15, ty = tid >> 4;
    const int lr = tid >> 3;
    const int lc = (tid & 7) << 2;

    float rmax[8]; int ridx[8];
    #pragma unroll
    for (int i = 0; i < 8; ++i) { rmax[i] = -3.0e38f; ridx[i] = 0; }

    for (int nt = 0; nt < NCHUNK; nt += BN) {
        float acc[8][8] = {};
        for (int k0 = 0; k0 < DMODEL; k0 += BK) {
            #pragma unroll
            for (int p = 0; p < 4; ++p) {
                const int row = lr + p * 32;
                const float4 av = *(const float4*)(Q + (size_t)(s0 + row)      * DMODEL + k0 + lc);
                const float4 bv = *(const float4*)(K + (size_t)(t0 + nt + row) * DMODEL + k0 + lc);
                Qs[lc+0][row] = av.x; Qs[lc+1][row] = av.y; Qs[lc+2][row] = av.z; Qs[lc+3][row] = av.w;
                Ks[lc+0][row] = bv.x; Ks[lc+1][row] = bv.y; Ks[lc+2][row] = bv.z; Ks[lc+3][row] = bv.w;
            }
            __syncthreads();
            #pragma unroll
            for (int kk = 0; kk < BK; ++kk) {
                const float4 a0 = *(const float4*)&Qs[kk][ty << 2];
                const float4 a1 = *(const float4*)&Qs[kk][(ty << 2) + 64];
                const float4 b0 = *(const float4*)&Ks[kk][tx << 2];
                const float4 b1 = *(const float4*)&Ks[kk][(tx << 2) + 64];
                const float a[8]  = {a0.x, a0.y, a0.z, a0.w, a1.x, a1.y, a1.z, a1.w};
                const float bb[8] = {b0.x, b0.y, b0.z, b0.w, b1.x, b1.y, b1.z, b1.w};
                #pragma unroll
                for (int i = 0; i < 8; ++i)
                    #pragma unroll
                    for (int j = 0; j < 8; ++j)
                        acc[i][j] = fmaf(a[i], bb[j], acc[i][j]);
            }
            __syncthreads();
        }
        // running argmax update; j ascending == t ascending within a thread
        #pragma unroll
        for (int j = 0; j < 8; ++j) {
            const int t = t0 + nt + ((j < 4) ? (tx << 2) + j : 64 + (tx << 2) + (j - 4));
            #pragma unroll
            for (int i = 0; i < 8; ++i)
                if (acc[i][j] > rmax[i]) { rmax[i] = acc[i][j]; ridx[i] = t; }
        }
    }

    // Each output row's 16 partials sit in 16 consecutive lanes (same ty).
    #pragma unroll
    for (int i = 0; i < 8; ++i) {
        float mv = rmax[i]; int ii = ridx[i];
        #pragma unroll
        for (int off = 1; off < 16; off <<= 1) {
            const float om = __shfl_xor(mv, off, 64);
            const int   oi = __shfl_xor(ii, off, 64);
            if (om > mv || (om == mv && oi < ii)) { mv = om; ii = oi; }
        }
        if (tx == 0) {
            const int row = (i < 4) ? (ty << 2) + i : 64 + (ty << 2) + (i - 4);
            const size_t o = ((size_t)b * S_LEN + (s0 + row)) * NSPLIT + blockIdx.z;
            pmax[o] = mv;
            pidx[o] = ii;
        }
    }
}

// =====================================================================
// Kernel 3: reduce the NSPLIT partials, gather selected V row (or 0),
// and apply the output projection + bias.  64x64 block, 4x4 per thread.
// out[(s*B+b)*D + n] = attn_row . out_w[n,:] + out_b[n]
// =====================================================================
__global__ __launch_bounds__(256)
void gather_proj_kernel(const float* __restrict__ v,
                        const float* __restrict__ ow, const float* __restrict__ obias,
                        const float* __restrict__ pmax, const int* __restrict__ pidx,
                        float* __restrict__ out)
{
    constexpr int BM = 64, BN = 64, BK = 32;
    __shared__ float As[BK][BM + 4];
    __shared__ float Bs[BK][BN + 4];
    __shared__ int sidx[BM];

    const int tid = threadIdx.x;
    const int tx = tid & 15, ty = tid >> 4;
    const int m0 = blockIdx.x * BM;
    const int n0 = blockIdx.y * BN;
    const int lr = tid >> 3;
    const int lc = (tid & 7) << 2;

    if (tid < BM) {
        const int m = m0 + tid;
        const int s = m >> 2, b = m & 3;
        const float* pm = pmax + ((size_t)b * S_LEN + s) * NSPLIT;
        const int*   pi = pidx + ((size_t)b * S_LEN + s) * NSPLIT;
        float best = pm[0]; int bi = pi[0];
        #pragma unroll
        for (int c = 1; c < NSPLIT; ++c)
            if (pm[c] > best) { best = pm[c]; bi = pi[c]; }  // strict >, chunks ascending in t
        sidx[tid] = (best >= THRESHV) ? bi : -1;
    }
    __syncthreads();

    float acc[4][4] = {};

    for (int k0 = 0; k0 < DMODEL; k0 += BK) {
        const int i0 = sidx[lr];
        const int i1 = sidx[lr + 32];
        const int b0r = (m0 + lr) & 3;
        const int b1r = (m0 + lr + 32) & 3;
        float4 a0 = make_float4(0.f, 0.f, 0.f, 0.f);
        float4 a1 = make_float4(0.f, 0.f, 0.f, 0.f);
        if (i0 >= 0) a0 = *(const float4*)(v + ((size_t)b0r * S_LEN + i0) * DMODEL + k0 + lc);
        if (i1 >= 0) a1 = *(const float4*)(v + ((size_t)b1r * S_LEN + i1) * DMODEL + k0 + lc);
        const float4 w0 = *(const float4*)(ow + (size_t)(n0 + lr)      * DMODEL + k0 + lc);
        const float4 w1 = *(const float4*)(ow + (size_t)(n0 + lr + 32) * DMODEL + k0 + lc);
        As[lc+0][lr]    = a0.x; As[lc+1][lr]    = a0.y; As[lc+2][lr]    = a0.z; As[lc+3][lr]    = a0.w;
        As[lc+0][lr+32] = a1.x; As[lc+1][lr+32] = a1.y; As[lc+2][lr+32] = a1.z; As[lc+3][lr+32] = a1.w;
        Bs[lc+0][lr]    = w0.x; Bs[lc+1][lr]    = w0.y; Bs[lc+2][lr]    = w0.z; Bs[lc+3][lr]    = w0.w;
        Bs[lc+0][lr+32] = w1.x; Bs[lc+1][lr+32] = w1.y; Bs[lc+2][lr+32] = w1.z; Bs[lc+3][lr+32] = w1.w;
        __syncthreads();
        #pragma unroll
        for (int kk = 0; kk < BK; ++kk) {
            const float4 av = *(const float4*)&As[kk][ty << 2];
            const float4 bv = *(const float4*)&Bs[kk][tx << 2];
            const float a[4] = {av.x, av.y, av.z, av.w};
            const float b[4] = {bv.x, bv.y, bv.z, bv.w};
            #pragma unroll
            for (int i = 0; i < 4; ++i)
                #pragma unroll
                for (int j = 0; j < 4; ++j)
                    acc[i][j] = fmaf(a[i], b[j], acc[i][j]);
        }
        __syncthreads();
    }

    const float4 biasv = *(const float4*)(obias + n0 + (tx << 2));
    #pragma unroll
    for (int i = 0; i < 4; ++i) {
        const int m = m0 + (ty << 2) + i;
        float4 r;
        r.x = acc[i][0] + biasv.x;
        r.y = acc[i][1] + biasv.y;
        r.z = acc[i][2] + biasv.z;
        r.w = acc[i][3] + biasv.w;
        *(float4*)(out + (size_t)m * DMODEL + n0 + (tx << 2)) = r;
    }
}

// =====================================================================
extern "C" void kernel_launch(void* const* d_in, const int* in_sizes, int n_in,
                              void* d_out, int out_size, void* d_ws, size_t ws_size,
                              hipStream_t stream)
{
    const float* x  = (const float*)d_in[0];
    const float* qw = (const float*)d_in[1];
    const float* qb = (const float*)d_in[2];
    const float* kw = (const float*)d_in[3];
    const float* kb = (const float*)d_in[4];
    const float* vw = (const float*)d_in[5];
    const float* vb = (const float*)d_in[6];
    const float* ow = (const float*)d_in[7];
    const float* ob = (const float*)d_in[8];
    float* out = (float*)d_out;

    const size_t SBD = (size_t)S_LEN * BATCH * DMODEL;   // 8,388,608
    float* qo   = (float*)d_ws;
    float* ko   = qo + SBD;
    float* vo   = ko + SBD;
    float* pmax = vo + SBD;
    int*   pidx = (int*)(pmax + (size_t)BATCH * S_LEN * NSPLIT);
    // total ws use: 3*32MB + ~1MB  (~102 MB)

    dim3 g1((S_LEN * BATCH) / 128, DMODEL / 128, 3); // 128 x 4 x 3
    qkv_gemm_kernel<<<g1, 256, 0, stream>>>(x, qw, qb, kw, kb, vw, vb, qo, ko, vo);

    dim3 g2(S_LEN / 128, BATCH, NSPLIT);             // 32 x 4 x 8
    score_argmax_kernel<<<g2, 256, 0, stream>>>(qo, ko, pmax, pidx);

    dim3 g3((S_LEN * BATCH) / 64, DMODEL / 64);      // 256 x 8
    gather_proj_kernel<<<g3, 256, 0, stream>>>(vo, ow, ob, pmax, pidx, out);
}

// Round 5
// 908.167 us; speedup vs baseline: 1.5188x; 1.5188x over previous
//
#include <hip/hip_runtime.h>
#include <cstdint>
#include <cstddef>

#define S_LEN 4096
#define BATCH 4
#define DMODEL 512
#define THRESHV 0.95f
#define NSPLIT 8
#define NCHUNK (S_LEN / NSPLIT)

typedef __attribute__((ext_vector_type(8))) short bf16x8;
typedef __attribute__((ext_vector_type(4))) float f32x4;

// =====================================================================
// Kernel 1: fused QKV projection (fp32 VALU, 128x128 tile, 8x8/thread).
// UNCHANGED from round 3 (passing, absmax 0.0).
// =====================================================================
__global__ __launch_bounds__(256)
void qkv_gemm_kernel(const float* __restrict__ x,
                     const float* __restrict__ qw, const float* __restrict__ qbias,
                     const float* __restrict__ kw, const float* __restrict__ kbias,
                     const float* __restrict__ vw, const float* __restrict__ vbias,
                     float* __restrict__ qo, float* __restrict__ ko, float* __restrict__ vo)
{
    constexpr int BM = 128, BN = 128, BK = 32;
    const float* w; const float* bias; float* out;
    if (blockIdx.z == 0)      { w = qw; bias = qbias; out = qo; }
    else if (blockIdx.z == 1) { w = kw; bias = kbias; out = ko; }
    else                      { w = vw; bias = vbias; out = vo; }

    __shared__ float As[BK][BM + 4];
    __shared__ float Bs[BK][BN + 4];

    const int tid = threadIdx.x;
    const int tx = tid & 15, ty = tid >> 4;
    const int lr = tid >> 3;
    const int lc = (tid & 7) << 2;
    const int m0 = blockIdx.x * BM;
    const int n0 = blockIdx.y * BN;

    float acc[8][8] = {};

    for (int k0 = 0; k0 < DMODEL; k0 += BK) {
        #pragma unroll
        for (int p = 0; p < 4; ++p) {
            const int row = lr + p * 32;
            const float4 av = *(const float4*)(x + (size_t)(m0 + row) * DMODEL + k0 + lc);
            const float4 bv = *(const float4*)(w + (size_t)(n0 + row) * DMODEL + k0 + lc);
            As[lc+0][row] = av.x; As[lc+1][row] = av.y; As[lc+2][row] = av.z; As[lc+3][row] = av.w;
            Bs[lc+0][row] = bv.x; Bs[lc+1][row] = bv.y; Bs[lc+2][row] = bv.z; Bs[lc+3][row] = bv.w;
        }
        __syncthreads();
        #pragma unroll
        for (int kk = 0; kk < BK; ++kk) {
            const float4 a0 = *(const float4*)&As[kk][ty << 2];
            const float4 a1 = *(const float4*)&As[kk][(ty << 2) + 64];
            const float4 b0 = *(const float4*)&Bs[kk][tx << 2];
            const float4 b1 = *(const float4*)&Bs[kk][(tx << 2) + 64];
            const float a[8]  = {a0.x, a0.y, a0.z, a0.w, a1.x, a1.y, a1.z, a1.w};
            const float bb[8] = {b0.x, b0.y, b0.z, b0.w, b1.x, b1.y, b1.z, b1.w};
            #pragma unroll
            for (int i = 0; i < 8; ++i)
                #pragma unroll
                for (int j = 0; j < 8; ++j)
                    acc[i][j] = fmaf(a[i], bb[j], acc[i][j]);
        }
        __syncthreads();
    }

    const float4 bias0 = *(const float4*)(bias + n0 + (tx << 2));
    const float4 bias1 = *(const float4*)(bias + n0 + (tx << 2) + 64);
    #pragma unroll
    for (int i = 0; i < 8; ++i) {
        const int m = m0 + ((i < 4) ? (ty << 2) + i : 64 + (ty << 2) + (i - 4));
        const int s = m >> 2, b = m & 3;
        float* orow = out + ((size_t)b * S_LEN + s) * DMODEL;
        float4 r0, r1;
        r0.x = acc[i][0] + bias0.x; r0.y = acc[i][1] + bias0.y;
        r0.z = acc[i][2] + bias0.z; r0.w = acc[i][3] + bias0.w;
        r1.x = acc[i][4] + bias1.x; r1.y = acc[i][5] + bias1.y;
        r1.z = acc[i][6] + bias1.z; r1.w = acc[i][7] + bias1.w;
        *(float4*)(orow + n0 + (tx << 2))      = r0;
        *(float4*)(orow + n0 + (tx << 2) + 64) = r1;
    }
}

// =====================================================================
// split8_store: 8 fp32 -> 3 planes of 8 bf16 (truncation split).
// q = h + m + l + eps, |eps| <= |q|*2^-24; subtractions are exact.
// =====================================================================
__device__ __forceinline__ void split8_store(const float* __restrict__ g,
                                             unsigned short* __restrict__ ph,
                                             unsigned short* __restrict__ pm,
                                             unsigned short* __restrict__ pl)
{
    const float4 f0 = *(const float4*)g;
    const float4 f1 = *(const float4*)(g + 4);
    const float f[8] = {f0.x, f0.y, f0.z, f0.w, f1.x, f1.y, f1.z, f1.w};
    unsigned int uh[8], um[8], ul[8];
    #pragma unroll
    for (int i = 0; i < 8; ++i) {
        const unsigned int u  = __float_as_uint(f[i]);
        const unsigned int hb = u & 0xFFFF0000u;
        const float r1 = f[i] - __uint_as_float(hb);
        const unsigned int u1 = __float_as_uint(r1);
        const unsigned int mb = u1 & 0xFFFF0000u;
        const float r2 = r1 - __uint_as_float(mb);
        uh[i] = u; um[i] = u1; ul[i] = __float_as_uint(r2);
    }
    uint4 wh, wm, wl;
    wh.x = (uh[0] >> 16) | (uh[1] & 0xFFFF0000u);
    wh.y = (uh[2] >> 16) | (uh[3] & 0xFFFF0000u);
    wh.z = (uh[4] >> 16) | (uh[5] & 0xFFFF0000u);
    wh.w = (uh[6] >> 16) | (uh[7] & 0xFFFF0000u);
    wm.x = (um[0] >> 16) | (um[1] & 0xFFFF0000u);
    wm.y = (um[2] >> 16) | (um[3] & 0xFFFF0000u);
    wm.z = (um[4] >> 16) | (um[5] & 0xFFFF0000u);
    wm.w = (um[6] >> 16) | (um[7] & 0xFFFF0000u);
    wl.x = (ul[0] >> 16) | (ul[1] & 0xFFFF0000u);
    wl.y = (ul[2] >> 16) | (ul[3] & 0xFFFF0000u);
    wl.z = (ul[4] >> 16) | (ul[5] & 0xFFFF0000u);
    wl.w = (ul[6] >> 16) | (ul[7] & 0xFFFF0000u);
    *(uint4*)ph = wh; *(uint4*)pm = wm; *(uint4*)pl = wl;
}

// swizzled element offset within a 32-elem (64B) LDS row: 16B slot index
// XORed with (row>>1)&3.  Same involution on write and read paths.
__device__ __forceinline__ int swz(int row, int slot) {
    return (slot ^ ((row >> 1) & 3)) * 8;
}

// =====================================================================
// Kernel 2: scores = Q K^T via 6-term split-bf16 MFMA + fused argmax.
// 4 waves, 2x2 wave tiles of 64x64 (4x4 MFMA 16x16x32 each).
// RACE FIX vs round 4: waves sharing the same q-rows (0&1, 2&3) combine
// their per-row (max,idx) partials through LDS; one writer per row.
// LDS rows swizzled (swz) so frag reads are 2-way bank-aliased (free).
// First-occurrence argmax: per-lane scan ascending in t, strict >;
// all cross-merges tie-break toward the smaller index.
// =====================================================================
__global__ __launch_bounds__(256, 2)
void score_argmax_kernel(const float* __restrict__ q, const float* __restrict__ k,
                         float* __restrict__ pmax, int* __restrict__ pidx)
{
    __shared__ unsigned short Qh[128][32], Qm[128][32], Ql[128][32];
    __shared__ unsigned short Kh[128][32], Km[128][32], Kl[128][32];
    __shared__ float redM[4][64];
    __shared__ int   redI[4][64];

    const int tid  = threadIdx.x;
    const int lane = tid & 63;
    const int wv   = tid >> 6;           // wave 0..3
    const int wrow = (wv >> 1) * 64;     // wave tile origin
    const int wcol = (wv & 1) * 64;
    const int fr   = lane & 15;          // fragment row/col index
    const int fs   = lane >> 4;          // fragment k slot (0..3)

    const int b  = blockIdx.y;
    const int s0 = blockIdx.x * 128;
    const int t0 = blockIdx.z * NCHUNK;
    const float* Qg = q + (size_t)b * S_LEN * DMODEL;
    const float* Kg = k + (size_t)b * S_LEN * DMODEL;

    // staging: pair p -> (row=p>>2, slot=p&3); thread handles p=tid, tid+256
    const int r0s = tid >> 2,         sl0 = tid & 3;
    const int r1s = (tid + 256) >> 2, sl1 = (tid + 256) & 3;

    float rmax[16]; int ridx[16];
    #pragma unroll
    for (int s = 0; s < 16; ++s) { rmax[s] = -3.0e38f; ridx[s] = 0; }

    for (int nt = 0; nt < NCHUNK / 128; ++nt) {
        const int trow0 = t0 + nt * 128;
        f32x4 acc[4][4] = {};

        for (int k0 = 0; k0 < DMODEL; k0 += 32) {
            __syncthreads();   // previous step's reads complete
            split8_store(Qg + (size_t)(s0 + r0s) * DMODEL + k0 + sl0 * 8,
                         &Qh[r0s][swz(r0s, sl0)], &Qm[r0s][swz(r0s, sl0)], &Ql[r0s][swz(r0s, sl0)]);
            split8_store(Qg + (size_t)(s0 + r1s) * DMODEL + k0 + sl1 * 8,
                         &Qh[r1s][swz(r1s, sl1)], &Qm[r1s][swz(r1s, sl1)], &Ql[r1s][swz(r1s, sl1)]);
            split8_store(Kg + (size_t)(trow0 + r0s) * DMODEL + k0 + sl0 * 8,
                         &Kh[r0s][swz(r0s, sl0)], &Km[r0s][swz(r0s, sl0)], &Kl[r0s][swz(r0s, sl0)]);
            split8_store(Kg + (size_t)(trow0 + r1s) * DMODEL + k0 + sl1 * 8,
                         &Kh[r1s][swz(r1s, sl1)], &Km[r1s][swz(r1s, sl1)], &Kl[r1s][swz(r1s, sl1)]);
            __syncthreads();   // staged data visible

            bf16x8 aH[4], aM[4], aL[4];
            #pragma unroll
            for (int rt = 0; rt < 4; ++rt) {
                const int r = wrow + rt * 16 + fr;
                const int o = swz(r, fs);
                aH[rt] = *(const bf16x8*)&Qh[r][o];
                aM[rt] = *(const bf16x8*)&Qm[r][o];
                aL[rt] = *(const bf16x8*)&Ql[r][o];
            }
            #pragma unroll
            for (int ct = 0; ct < 4; ++ct) {
                const int c = wcol + ct * 16 + fr;
                const int o = swz(c, fs);
                const bf16x8 bH = *(const bf16x8*)&Kh[c][o];
                const bf16x8 bM = *(const bf16x8*)&Km[c][o];
                const bf16x8 bL = *(const bf16x8*)&Kl[c][o];
                #pragma unroll
                for (int rt = 0; rt < 4; ++rt) {
                    f32x4 a = acc[rt][ct];
                    a = __builtin_amdgcn_mfma_f32_16x16x32_bf16(aH[rt], bH, a, 0, 0, 0);
                    a = __builtin_amdgcn_mfma_f32_16x16x32_bf16(aH[rt], bM, a, 0, 0, 0);
                    a = __builtin_amdgcn_mfma_f32_16x16x32_bf16(aM[rt], bH, a, 0, 0, 0);
                    a = __builtin_amdgcn_mfma_f32_16x16x32_bf16(aM[rt], bM, a, 0, 0, 0);
                    a = __builtin_amdgcn_mfma_f32_16x16x32_bf16(aH[rt], bL, a, 0, 0, 0);
                    a = __builtin_amdgcn_mfma_f32_16x16x32_bf16(aL[rt], bH, a, 0, 0, 0);
                    acc[rt][ct] = a;
                }
            }
        }

        // running argmax; per lane, t ascends with ct (nt ascends outer)
        #pragma unroll
        for (int rt = 0; rt < 4; ++rt)
            #pragma unroll
            for (int ct = 0; ct < 4; ++ct) {
                const int t = trow0 + wcol + ct * 16 + fr;
                #pragma unroll
                for (int r = 0; r < 4; ++r) {
                    const float sc = acc[rt][ct][r];
                    if (sc > rmax[rt * 4 + r]) { rmax[rt * 4 + r] = sc; ridx[rt * 4 + r] = t; }
                }
            }
    }

    // within-wave reduce: row (rt, fs, r) partials live in the 16 lanes
    // of equal fs; tie -> smaller idx.  Deposit per-wave results in LDS.
    #pragma unroll
    for (int s = 0; s < 16; ++s) {
        float mv = rmax[s]; int ii = ridx[s];
        #pragma unroll
        for (int off = 1; off < 16; off <<= 1) {
            const float om = __shfl_xor(mv, off, 64);
            const int   oi = __shfl_xor(ii, off, 64);
            if (om > mv || (om == mv && oi < ii)) { mv = om; ii = oi; }
        }
        if (fr == 0) {
            const int row_local = (s >> 2) * 16 + fs * 4 + (s & 3);
            redM[wv][row_local] = mv;
            redI[wv][row_local] = ii;
        }
    }
    __syncthreads();

    // cross-wave combine (waves {0,1} share rows 0..63; {2,3} share 64..127)
    if ((wv & 1) == 0) {
        const float m0v = redM[wv][lane];
        const float m1v = redM[wv + 1][lane];
        const int   i0v = redI[wv][lane];
        const int   i1v = redI[wv + 1][lane];
        float mv = m0v; int ii = i0v;
        if (m1v > mv || (m1v == mv && i1v < ii)) { mv = m1v; ii = i1v; }
        const int row = s0 + wrow + lane;
        const size_t o = ((size_t)b * S_LEN + row) * NSPLIT + blockIdx.z;
        pmax[o] = mv; pidx[o] = ii;
    }
}

// =====================================================================
// Kernel 3: reduce NSPLIT partials, gather selected V row (or 0), apply
// output projection + bias.  UNCHANGED from round 3.
// =====================================================================
__global__ __launch_bounds__(256)
void gather_proj_kernel(const float* __restrict__ v,
                        const float* __restrict__ ow, const float* __restrict__ obias,
                        const float* __restrict__ pmax, const int* __restrict__ pidx,
                        float* __restrict__ out)
{
    constexpr int BM = 64, BN = 64, BK = 32;
    __shared__ float As[BK][BM + 4];
    __shared__ float Bs[BK][BN + 4];
    __shared__ int sidx[BM];

    const int tid = threadIdx.x;
    const int tx = tid & 15, ty = tid >> 4;
    const int m0 = blockIdx.x * BM;
    const int n0 = blockIdx.y * BN;
    const int lr = tid >> 3;
    const int lc = (tid & 7) << 2;

    if (tid < BM) {
        const int m = m0 + tid;
        const int s = m >> 2, b = m & 3;
        const float* pm = pmax + ((size_t)b * S_LEN + s) * NSPLIT;
        const int*   pi = pidx + ((size_t)b * S_LEN + s) * NSPLIT;
        float best = pm[0]; int bi = pi[0];
        #pragma unroll
        for (int c = 1; c < NSPLIT; ++c)
            if (pm[c] > best) { best = pm[c]; bi = pi[c]; }
        sidx[tid] = (best >= THRESHV) ? bi : -1;
    }
    __syncthreads();

    float acc[4][4] = {};

    for (int k0 = 0; k0 < DMODEL; k0 += BK) {
        const int i0 = sidx[lr];
        const int i1 = sidx[lr + 32];
        const int b0r = (m0 + lr) & 3;
        const int b1r = (m0 + lr + 32) & 3;
        float4 a0 = make_float4(0.f, 0.f, 0.f, 0.f);
        float4 a1 = make_float4(0.f, 0.f, 0.f, 0.f);
        if (i0 >= 0) a0 = *(const float4*)(v + ((size_t)b0r * S_LEN + i0) * DMODEL + k0 + lc);
        if (i1 >= 0) a1 = *(const float4*)(v + ((size_t)b1r * S_LEN + i1) * DMODEL + k0 + lc);
        const float4 w0 = *(const float4*)(ow + (size_t)(n0 + lr)      * DMODEL + k0 + lc);
        const float4 w1 = *(const float4*)(ow + (size_t)(n0 + lr + 32) * DMODEL + k0 + lc);
        As[lc+0][lr]    = a0.x; As[lc+1][lr]    = a0.y; As[lc+2][lr]    = a0.z; As[lc+3][lr]    = a0.w;
        As[lc+0][lr+32] = a1.x; As[lc+1][lr+32] = a1.y; As[lc+2][lr+32] = a1.z; As[lc+3][lr+32] = a1.w;
        Bs[lc+0][lr]    = w0.x; Bs[lc+1][lr]    = w0.y; Bs[lc+2][lr]    = w0.z; Bs[lc+3][lr]    = w0.w;
        Bs[lc+0][lr+32] = w1.x; Bs[lc+1][lr+32] = w1.y; Bs[lc+2][lr+32] = w1.z; Bs[lc+3][lr+32] = w1.w;
        __syncthreads();
        #pragma unroll
        for (int kk = 0; kk < BK; ++kk) {
            const float4 av = *(const float4*)&As[kk][ty << 2];
            const float4 bv = *(const float4*)&Bs[kk][tx << 2];
            const float a[4] = {av.x, av.y, av.z, av.w};
            const float bb[4] = {bv.x, bv.y, bv.z, bv.w};
            #pragma unroll
            for (int i = 0; i < 4; ++i)
                #pragma unroll
                for (int j = 0; j < 4; ++j)
                    acc[i][j] = fmaf(a[i], bb[j], acc[i][j]);
        }
        __syncthreads();
    }

    const float4 biasv = *(const float4*)(obias + n0 + (tx << 2));
    #pragma unroll
    for (int i = 0; i < 4; ++i) {
        const int m = m0 + (ty << 2) + i;
        float4 r;
        r.x = acc[i][0] + biasv.x;
        r.y = acc[i][1] + biasv.y;
        r.z = acc[i][2] + biasv.z;
        r.w = acc[i][3] + biasv.w;
        *(float4*)(out + (size_t)m * DMODEL + n0 + (tx << 2)) = r;
    }
}

// =====================================================================
extern "C" void kernel_launch(void* const* d_in, const int* in_sizes, int n_in,
                              void* d_out, int out_size, void* d_ws, size_t ws_size,
                              hipStream_t stream)
{
    const float* x  = (const float*)d_in[0];
    const float* qw = (const float*)d_in[1];
    const float* qb = (const float*)d_in[2];
    const float* kw = (const float*)d_in[3];
    const float* kb = (const float*)d_in[4];
    const float* vw = (const float*)d_in[5];
    const float* vb = (const float*)d_in[6];
    const float* ow = (const float*)d_in[7];
    const float* ob = (const float*)d_in[8];
    float* out = (float*)d_out;

    const size_t SBD = (size_t)S_LEN * BATCH * DMODEL;   // 8,388,608
    float* qo   = (float*)d_ws;
    float* ko   = qo + SBD;
    float* vo   = ko + SBD;
    float* pmax = vo + SBD;
    int*   pidx = (int*)(pmax + (size_t)BATCH * S_LEN * NSPLIT);
    // total ws use: 3*32MB + ~1MB  (~102 MB)

    dim3 g1((S_LEN * BATCH) / 128, DMODEL / 128, 3); // 128 x 4 x 3
    qkv_gemm_kernel<<<g1, 256, 0, stream>>>(x, qw, qb, kw, kb, vw, vb, qo, ko, vo);

    dim3 g2(S_LEN / 128, BATCH, NSPLIT);             // 32 x 4 x 8
    score_argmax_kernel<<<g2, 256, 0, stream>>>(qo, ko, pmax, pidx);

    dim3 g3((S_LEN * BATCH) / 64, DMODEL / 64);      // 256 x 8
    gather_proj_kernel<<<g3, 256, 0, stream>>>(vo, ow, ob, pmax, pidx, out);
}

// Round 7
// 656.473 us; speedup vs baseline: 2.1011x; 1.3834x over previous
//
#include <hip/hip_runtime.h>
#include <cstdint>
#include <cstddef>

#define S_LEN 4096
#define BATCH 4
#define DMODEL 512
#define THRESHV 0.95f
#define NSPLIT 8
#define NCHUNK (S_LEN / NSPLIT)
#define SBLKS (S_LEN / 128)    // 32 row-tiles per batch
#define KSTEPS (DMODEL / 32)   // 16 k-steps

typedef __attribute__((ext_vector_type(8))) short bf16x8;
typedef __attribute__((ext_vector_type(4))) float f32x4;

// pre-tiled plane layout: [b][s_blk][k_step][row 128][swz slot 4][e 8] bf16,
// i.e. each (b,s_blk,k_step) is a 4096-ushort (8 KB) block = k2's LDS image.
__device__ __forceinline__ size_t tile_base(int b, int sblk, int kstep) {
    return ((((size_t)b * SBLKS + sblk) * KSTEPS) + kstep) << 12;
}

// swizzled elem offset within a 32-elem (64B) row: 16B slot XOR (row>>1)&3.
__device__ __forceinline__ int swz(int row, int slot) {
    return (slot ^ ((row >> 1) & 3)) * 8;
}

// =====================================================================
// split8_store: 8 fp32 -> 3 planes of 8 bf16 (truncation split).
// v = h + m + l + eps, |eps| <= |v|*2^-24; subtractions exact.
// =====================================================================
__device__ __forceinline__ void split8_store(const float* __restrict__ g,
                                             unsigned short* __restrict__ ph,
                                             unsigned short* __restrict__ pm,
                                             unsigned short* __restrict__ pl)
{
    const float4 f0 = *(const float4*)g;
    const float4 f1 = *(const float4*)(g + 4);
    const float f[8] = {f0.x, f0.y, f0.z, f0.w, f1.x, f1.y, f1.z, f1.w};
    unsigned int uh[8], um[8], ul[8];
    #pragma unroll
    for (int i = 0; i < 8; ++i) {
        const unsigned int u  = __float_as_uint(f[i]);
        const float e1 = f[i] - __uint_as_float(u & 0xFFFF0000u);
        const unsigned int u1 = __float_as_uint(e1);
        const float e2 = e1 - __uint_as_float(u1 & 0xFFFF0000u);
        uh[i] = u; um[i] = u1; ul[i] = __float_as_uint(e2);
    }
    uint4 wh, wm, wl;
    wh.x = (uh[0] >> 16) | (uh[1] & 0xFFFF0000u);
    wh.y = (uh[2] >> 16) | (uh[3] & 0xFFFF0000u);
    wh.z = (uh[4] >> 16) | (uh[5] & 0xFFFF0000u);
    wh.w = (uh[6] >> 16) | (uh[7] & 0xFFFF0000u);
    wm.x = (um[0] >> 16) | (um[1] & 0xFFFF0000u);
    wm.y = (um[2] >> 16) | (um[3] & 0xFFFF0000u);
    wm.z = (um[4] >> 16) | (um[5] & 0xFFFF0000u);
    wm.w = (um[6] >> 16) | (um[7] & 0xFFFF0000u);
    wl.x = (ul[0] >> 16) | (ul[1] & 0xFFFF0000u);
    wl.y = (ul[2] >> 16) | (ul[3] & 0xFFFF0000u);
    wl.z = (ul[4] >> 16) | (ul[5] & 0xFFFF0000u);
    wl.w = (ul[6] >> 16) | (ul[7] & 0xFFFF0000u);
    *(uint4*)ph = wh; *(uint4*)pm = wm; *(uint4*)pl = wl;
}

// =====================================================================
// Kernel 1: QKV projection on MFMA (round-5 k2 skeleton: 4 waves, 2x2
// wave tiles 64x64, 6-term split-bf16).  z=0/1 -> q/k: 6 terms, epilogue
// splits (acc+bias) into 3 bf16 planes written PRE-TILED+PRE-SWIZZLED
// (k2's exact LDS image).  z=2 -> v: 3 terms (bf16-grade), stored bf16.
// =====================================================================
__global__ __launch_bounds__(256, 2)
void qkv_mfma_kernel(const float* __restrict__ x,
                     const float* __restrict__ qw, const float* __restrict__ qbias,
                     const float* __restrict__ kw, const float* __restrict__ kbias,
                     const float* __restrict__ vw, const float* __restrict__ vbias,
                     unsigned short* __restrict__ qh_t, unsigned short* __restrict__ qm_t,
                     unsigned short* __restrict__ ql_t, unsigned short* __restrict__ kh_t,
                     unsigned short* __restrict__ km_t, unsigned short* __restrict__ kl_t,
                     unsigned short* __restrict__ vb16)
{
    __shared__ unsigned short Xh[128][32], Xm[128][32], Xl[128][32];
    __shared__ unsigned short Wh[128][32], Wm[128][32], Wl[128][32];

    const int z = blockIdx.z;
    const float* w; const float* bias;
    if (z == 0)      { w = qw; bias = qbias; }
    else if (z == 1) { w = kw; bias = kbias; }
    else             { w = vw; bias = vbias; }
    const bool full6 = (z < 2);

    const int tid = threadIdx.x, lane = tid & 63, wv = tid >> 6;
    const int wrow = (wv >> 1) * 64, wcol = (wv & 1) * 64;
    const int fr = lane & 15, fs = lane >> 4;
    const int m0 = blockIdx.x * 128, n0 = blockIdx.y * 128;

    const int r0s = tid >> 2,         sl0 = tid & 3;
    const int r1s = (tid + 256) >> 2, sl1 = (tid + 256) & 3;

    f32x4 acc[4][4] = {};

    for (int k0 = 0; k0 < DMODEL; k0 += 32) {
        __syncthreads();   // previous step's reads complete
        split8_store(x + (size_t)(m0 + r0s) * DMODEL + k0 + sl0 * 8,
                     &Xh[r0s][swz(r0s, sl0)], &Xm[r0s][swz(r0s, sl0)], &Xl[r0s][swz(r0s, sl0)]);
        split8_store(x + (size_t)(m0 + r1s) * DMODEL + k0 + sl1 * 8,
                     &Xh[r1s][swz(r1s, sl1)], &Xm[r1s][swz(r1s, sl1)], &Xl[r1s][swz(r1s, sl1)]);
        split8_store(w + (size_t)(n0 + r0s) * DMODEL + k0 + sl0 * 8,
                     &Wh[r0s][swz(r0s, sl0)], &Wm[r0s][swz(r0s, sl0)], &Wl[r0s][swz(r0s, sl0)]);
        split8_store(w + (size_t)(n0 + r1s) * DMODEL + k0 + sl1 * 8,
                     &Wh[r1s][swz(r1s, sl1)], &Wm[r1s][swz(r1s, sl1)], &Wl[r1s][swz(r1s, sl1)]);
        __syncthreads();   // staged data visible

        bf16x8 aH[4], aM[4], aL[4];
        #pragma unroll
        for (int rt = 0; rt < 4; ++rt) {
            const int r = wrow + rt * 16 + fr;
            const int o = swz(r, fs);
            aH[rt] = *(const bf16x8*)&Xh[r][o];
            aM[rt] = *(const bf16x8*)&Xm[r][o];
            if (full6) aL[rt] = *(const bf16x8*)&Xl[r][o];
        }
        #pragma unroll
        for (int ct = 0; ct < 4; ++ct) {
            const int c = wcol + ct * 16 + fr;
            const int o = swz(c, fs);
            const bf16x8 bH = *(const bf16x8*)&Wh[c][o];
            const bf16x8 bM = *(const bf16x8*)&Wm[c][o];
            bf16x8 bL;
            if (full6) bL = *(const bf16x8*)&Wl[c][o];
            #pragma unroll
            for (int rt = 0; rt < 4; ++rt) {
                f32x4 a = acc[rt][ct];
                a = __builtin_amdgcn_mfma_f32_16x16x32_bf16(aH[rt], bH, a, 0, 0, 0);
                a = __builtin_amdgcn_mfma_f32_16x16x32_bf16(aH[rt], bM, a, 0, 0, 0);
                a = __builtin_amdgcn_mfma_f32_16x16x32_bf16(aM[rt], bH, a, 0, 0, 0);
                if (full6) {
                    a = __builtin_amdgcn_mfma_f32_16x16x32_bf16(aM[rt], bM, a, 0, 0, 0);
                    a = __builtin_amdgcn_mfma_f32_16x16x32_bf16(aH[rt], bL, a, 0, 0, 0);
                    a = __builtin_amdgcn_mfma_f32_16x16x32_bf16(aL[rt], bH, a, 0, 0, 0);
                }
                acc[rt][ct] = a;
            }
        }
    }

    // C layout (verified rounds 3/5): row m = m0+wrow+rt*16+fs*4+r,
    // col n = n0+wcol+ct*16+fr.  m = s*BATCH + b.
    if (z < 2) {
        unsigned short* ph = (z == 0) ? qh_t : kh_t;
        unsigned short* pm = (z == 0) ? qm_t : km_t;
        unsigned short* pl = (z == 0) ? ql_t : kl_t;
        #pragma unroll
        for (int ct = 0; ct < 4; ++ct) {
            const int n = n0 + wcol + ct * 16 + fr;
            const float bn = bias[n];
            const int kstep = n >> 5, slot = (n >> 3) & 3, e = n & 7;
            #pragma unroll
            for (int rt = 0; rt < 4; ++rt)
                #pragma unroll
                for (int r = 0; r < 4; ++r) {
                    const int m = m0 + wrow + rt * 16 + fs * 4 + r;
                    const int s = m >> 2, bb = m & 3;
                    const float val = acc[rt][ct][r] + bn;
                    const unsigned int u = __float_as_uint(val);
                    const float e1 = val - __uint_as_float(u & 0xFFFF0000u);
                    const unsigned int u1 = __float_as_uint(e1);
                    const float e2 = e1 - __uint_as_float(u1 & 0xFFFF0000u);
                    const unsigned int u2 = __float_as_uint(e2);
                    const size_t off = tile_base(bb, s >> 7, kstep)
                                     + (size_t)((s & 127) << 5)
                                     + ((slot ^ ((s >> 1) & 3)) << 3) + e;
                    ph[off] = (unsigned short)(u >> 16);
                    pm[off] = (unsigned short)(u1 >> 16);
                    pl[off] = (unsigned short)(u2 >> 16);
                }
        }
    } else {
        #pragma unroll
        for (int ct = 0; ct < 4; ++ct) {
            const int n = n0 + wcol + ct * 16 + fr;
            const float bn = bias[n];
            #pragma unroll
            for (int rt = 0; rt < 4; ++rt)
                #pragma unroll
                for (int r = 0; r < 4; ++r) {
                    const int m = m0 + wrow + rt * 16 + fs * 4 + r;
                    const int s = m >> 2, bb = m & 3;
                    const float val = acc[rt][ct][r] + bn;
                    const unsigned int u = __float_as_uint(val);
                    vb16[((size_t)bb * S_LEN + s) * DMODEL + n] =
                        (unsigned short)((u + 0x7FFFu + ((u >> 16) & 1u)) >> 16);  // RN
                }
        }
    }
}

// =====================================================================
// Kernel 2: scores = Q K^T via 6-term split-bf16 MFMA + fused argmax.
// Planes arrive pre-tiled+pre-swizzled: staging = 12 coalesced uint4
// copies per thread, zero VALU.  Fragment contents bit-identical to
// round 5 (passing).  Race-free partial write: per-wave LDS deposit +
// cross-wave combine, one writer per (row, chunk).  First-occurrence
// argmax: scan ascending in t, strict >; merges tie-break smaller idx.
// =====================================================================
__global__ __launch_bounds__(256, 2)
void score_argmax_kernel(const unsigned short* __restrict__ qh, const unsigned short* __restrict__ qm,
                         const unsigned short* __restrict__ ql, const unsigned short* __restrict__ kh,
                         const unsigned short* __restrict__ km, const unsigned short* __restrict__ kl,
                         float* __restrict__ pmax, int* __restrict__ pidx)
{
    __shared__ unsigned short Qh[4096], Qm[4096], Ql[4096];
    __shared__ unsigned short Kh[4096], Km[4096], Kl[4096];
    __shared__ float redM[4][64];
    __shared__ int   redI[4][64];

    const int tid = threadIdx.x, lane = tid & 63, wv = tid >> 6;
    const int wrow = (wv >> 1) * 64, wcol = (wv & 1) * 64;
    const int fr = lane & 15, fs = lane >> 4;

    const int b = blockIdx.y, sblk = blockIdx.x, s0 = sblk * 128;
    const int to = tid << 3;   // this thread's 8-ushort (16B) staging offset

    float rmax[16]; int ridx[16];
    #pragma unroll
    for (int s = 0; s < 16; ++s) { rmax[s] = -3.0e38f; ridx[s] = 0; }

    for (int nt = 0; nt < NCHUNK / 128; ++nt) {
        const int tblk = blockIdx.z * (NCHUNK / 128) + nt;
        const int trow0 = tblk * 128;
        f32x4 acc[4][4] = {};

        for (int kstep = 0; kstep < KSTEPS; ++kstep) {
            __syncthreads();   // previous step's reads complete
            const size_t qb = tile_base(b, sblk, kstep) + to;
            const size_t kb = tile_base(b, tblk, kstep) + to;
            *(uint4*)&Qh[to]        = *(const uint4*)(qh + qb);
            *(uint4*)&Qm[to]        = *(const uint4*)(qm + qb);
            *(uint4*)&Ql[to]        = *(const uint4*)(ql + qb);
            *(uint4*)&Kh[to]        = *(const uint4*)(kh + kb);
            *(uint4*)&Km[to]        = *(const uint4*)(km + kb);
            *(uint4*)&Kl[to]        = *(const uint4*)(kl + kb);
            *(uint4*)&Qh[to + 2048] = *(const uint4*)(qh + qb + 2048);
            *(uint4*)&Qm[to + 2048] = *(const uint4*)(qm + qb + 2048);
            *(uint4*)&Ql[to + 2048] = *(const uint4*)(ql + qb + 2048);
            *(uint4*)&Kh[to + 2048] = *(const uint4*)(kh + kb + 2048);
            *(uint4*)&Km[to + 2048] = *(const uint4*)(km + kb + 2048);
            *(uint4*)&Kl[to + 2048] = *(const uint4*)(kl + kb + 2048);
            __syncthreads();   // staged data visible

            bf16x8 aH[4], aM[4], aL[4];
            #pragma unroll
            for (int rt = 0; rt < 4; ++rt) {
                const int r = wrow + rt * 16 + fr;
                const int o = r * 32 + swz(r, fs);
                aH[rt] = *(const bf16x8*)&Qh[o];
                aM[rt] = *(const bf16x8*)&Qm[o];
                aL[rt] = *(const bf16x8*)&Ql[o];
            }
            #pragma unroll
            for (int ct = 0; ct < 4; ++ct) {
                const int c = wcol + ct * 16 + fr;
                const int o = c * 32 + swz(c, fs);
                const bf16x8 bH = *(const bf16x8*)&Kh[o];
                const bf16x8 bM = *(const bf16x8*)&Km[o];
                const bf16x8 bL = *(const bf16x8*)&Kl[o];
                #pragma unroll
                for (int rt = 0; rt < 4; ++rt) {
                    f32x4 a = acc[rt][ct];
                    a = __builtin_amdgcn_mfma_f32_16x16x32_bf16(aH[rt], bH, a, 0, 0, 0);
                    a = __builtin_amdgcn_mfma_f32_16x16x32_bf16(aH[rt], bM, a, 0, 0, 0);
                    a = __builtin_amdgcn_mfma_f32_16x16x32_bf16(aM[rt], bH, a, 0, 0, 0);
                    a = __builtin_amdgcn_mfma_f32_16x16x32_bf16(aM[rt], bM, a, 0, 0, 0);
                    a = __builtin_amdgcn_mfma_f32_16x16x32_bf16(aH[rt], bL, a, 0, 0, 0);
                    a = __builtin_amdgcn_mfma_f32_16x16x32_bf16(aL[rt], bH, a, 0, 0, 0);
                    acc[rt][ct] = a;
                }
            }
        }

        // running argmax; per lane, t ascends with ct (nt ascends outer)
        #pragma unroll
        for (int rt = 0; rt < 4; ++rt)
            #pragma unroll
            for (int ct = 0; ct < 4; ++ct) {
                const int t = trow0 + wcol + ct * 16 + fr;
                #pragma unroll
                for (int r = 0; r < 4; ++r) {
                    const float sc = acc[rt][ct][r];
                    if (sc > rmax[rt * 4 + r]) { rmax[rt * 4 + r] = sc; ridx[rt * 4 + r] = t; }
                }
            }
    }

    // within-wave reduce (16 lanes of equal fs hold one row's partials)
    #pragma unroll
    for (int s = 0; s < 16; ++s) {
        float mv = rmax[s]; int ii = ridx[s];
        #pragma unroll
        for (int off = 1; off < 16; off <<= 1) {
            const float om = __shfl_xor(mv, off, 64);
            const int   oi = __shfl_xor(ii, off, 64);
            if (om > mv || (om == mv && oi < ii)) { mv = om; ii = oi; }
        }
        if (fr == 0) {
            const int row_local = (s >> 2) * 16 + fs * 4 + (s & 3);
            redM[wv][row_local] = mv;
            redI[wv][row_local] = ii;
        }
    }
    __syncthreads();

    // cross-wave combine (waves {0,1} share rows 0..63; {2,3} 64..127)
    if ((wv & 1) == 0) {
        const float m0v = redM[wv][lane];
        const float m1v = redM[wv + 1][lane];
        const int   i0v = redI[wv][lane];
        const int   i1v = redI[wv + 1][lane];
        float mv = m0v; int ii = i0v;
        if (m1v > mv || (m1v == mv && i1v < ii)) { mv = m1v; ii = i1v; }
        const int row = s0 + wrow + lane;
        const size_t o = ((size_t)b * S_LEN + row) * NSPLIT + blockIdx.z;
        pmax[o] = mv; pidx[o] = ii;
    }
}

// =====================================================================
// Kernel 3: reduce NSPLIT partials, gather selected V row (or 0), apply
// output projection + bias.  Round-3 structure; V is now bf16.
// =====================================================================
__global__ __launch_bounds__(256)
void gather_proj_kernel(const unsigned short* __restrict__ v,
                        const float* __restrict__ ow, const float* __restrict__ obias,
                        const float* __restrict__ pmax, const int* __restrict__ pidx,
                        float* __restrict__ out)
{
    constexpr int BM = 64, BN = 64, BK = 32;
    __shared__ float As[BK][BM + 4];
    __shared__ float Bs[BK][BN + 4];
    __shared__ int sidx[BM];

    const int tid = threadIdx.x;
    const int tx = tid & 15, ty = tid >> 4;
    const int m0 = blockIdx.x * BM;
    const int n0 = blockIdx.y * BN;
    const int lr = tid >> 3;
    const int lc = (tid & 7) << 2;

    if (tid < BM) {
        const int m = m0 + tid;
        const int s = m >> 2, b = m & 3;
        const float* pm = pmax + ((size_t)b * S_LEN + s) * NSPLIT;
        const int*   pi = pidx + ((size_t)b * S_LEN + s) * NSPLIT;
        float best = pm[0]; int bi = pi[0];
        #pragma unroll
        for (int c = 1; c < NSPLIT; ++c)
            if (pm[c] > best) { best = pm[c]; bi = pi[c]; }
        sidx[tid] = (best >= THRESHV) ? bi : -1;
    }
    __syncthreads();

    float acc[4][4] = {};

    for (int k0 = 0; k0 < DMODEL; k0 += BK) {
        const int i0 = sidx[lr];
        const int i1 = sidx[lr + 32];
        const int b0r = (m0 + lr) & 3;
        const int b1r = (m0 + lr + 32) & 3;
        float4 a0 = make_float4(0.f, 0.f, 0.f, 0.f);
        float4 a1 = make_float4(0.f, 0.f, 0.f, 0.f);
        if (i0 >= 0) {
            const uint2 rw = *(const uint2*)(v + ((size_t)b0r * S_LEN + i0) * DMODEL + k0 + lc);
            a0.x = __uint_as_float(rw.x << 16); a0.y = __uint_as_float(rw.x & 0xFFFF0000u);
            a0.z = __uint_as_float(rw.y << 16); a0.w = __uint_as_float(rw.y & 0xFFFF0000u);
        }
        if (i1 >= 0) {
            const uint2 rw = *(const uint2*)(v + ((size_t)b1r * S_LEN + i1) * DMODEL + k0 + lc);
            a1.x = __uint_as_float(rw.x << 16); a1.y = __uint_as_float(rw.x & 0xFFFF0000u);
            a1.z = __uint_as_float(rw.y << 16); a1.w = __uint_as_float(rw.y & 0xFFFF0000u);
        }
        const float4 w0 = *(const float4*)(ow + (size_t)(n0 + lr)      * DMODEL + k0 + lc);
        const float4 w1 = *(const float4*)(ow + (size_t)(n0 + lr + 32) * DMODEL + k0 + lc);
        As[lc+0][lr]    = a0.x; As[lc+1][lr]    = a0.y; As[lc+2][lr]    = a0.z; As[lc+3][lr]    = a0.w;
        As[lc+0][lr+32] = a1.x; As[lc+1][lr+32] = a1.y; As[lc+2][lr+32] = a1.z; As[lc+3][lr+32] = a1.w;
        Bs[lc+0][lr]    = w0.x; Bs[lc+1][lr]    = w0.y; Bs[lc+2][lr]    = w0.z; Bs[lc+3][lr]    = w0.w;
        Bs[lc+0][lr+32] = w1.x; Bs[lc+1][lr+32] = w1.y; Bs[lc+2][lr+32] = w1.z; Bs[lc+3][lr+32] = w1.w;
        __syncthreads();
        #pragma unroll
        for (int kk = 0; kk < BK; ++kk) {
            const float4 av = *(const float4*)&As[kk][ty << 2];
            const float4 bv = *(const float4*)&Bs[kk][tx << 2];
            const float a[4] = {av.x, av.y, av.z, av.w};
            const float bb[4] = {bv.x, bv.y, bv.z, bv.w};
            #pragma unroll
            for (int i = 0; i < 4; ++i)
                #pragma unroll
                for (int j = 0; j < 4; ++j)
                    acc[i][j] = fmaf(a[i], bb[j], acc[i][j]);
        }
        __syncthreads();
    }

    const float4 biasv = *(const float4*)(obias + n0 + (tx << 2));
    #pragma unroll
    for (int i = 0; i < 4; ++i) {
        const int m = m0 + (ty << 2) + i;
        float4 r;
        r.x = acc[i][0] + biasv.x;
        r.y = acc[i][1] + biasv.y;
        r.z = acc[i][2] + biasv.z;
        r.w = acc[i][3] + biasv.w;
        *(float4*)(out + (size_t)m * DMODEL + n0 + (tx << 2)) = r;
    }
}

// =====================================================================
extern "C" void kernel_launch(void* const* d_in, const int* in_sizes, int n_in,
                              void* d_out, int out_size, void* d_ws, size_t ws_size,
                              hipStream_t stream)
{
    const float* x  = (const float*)d_in[0];
    const float* qw = (const float*)d_in[1];
    const float* qbias = (const float*)d_in[2];
    const float* kw = (const float*)d_in[3];
    const float* kbias = (const float*)d_in[4];
    const float* vw = (const float*)d_in[5];
    const float* vbias = (const float*)d_in[6];
    const float* ow = (const float*)d_in[7];
    const float* obias = (const float*)d_in[8];
    float* out = (float*)d_out;

    const size_t SBD = (size_t)S_LEN * BATCH * DMODEL;   // 8,388,608
    unsigned short* qh_t = (unsigned short*)d_ws;        // 7 bf16 planes, 16 MB each
    unsigned short* qm_t = qh_t + SBD;
    unsigned short* ql_t = qm_t + SBD;
    unsigned short* kh_t = ql_t + SBD;
    unsigned short* km_t = kh_t + SBD;
    unsigned short* kl_t = km_t + SBD;
    unsigned short* vb16 = kl_t + SBD;
    float* pmax = (float*)(vb16 + SBD);
    int*   pidx = (int*)(pmax + (size_t)BATCH * S_LEN * NSPLIT);
    // total ws use: 7*16.78 MB + ~1 MB  (~118 MB)

    dim3 g1(128, 4, 3);                              // m-tiles x n-tiles x {q,k,v}
    qkv_mfma_kernel<<<g1, 256, 0, stream>>>(x, qw, qbias, kw, kbias, vw, vbias,
                                            qh_t, qm_t, ql_t, kh_t, km_t, kl_t, vb16);

    dim3 g2(S_LEN / 128, BATCH, NSPLIT);             // 32 x 4 x 8
    score_argmax_kernel<<<g2, 256, 0, stream>>>(qh_t, qm_t, ql_t, kh_t, km_t, kl_t, pmax, pidx);

    dim3 g3((S_LEN * BATCH) / 64, DMODEL / 64);      // 256 x 8
    gather_proj_kernel<<<g3, 256, 0, stream>>>(vb16, ow, obias, pmax, pidx, out);
}